// Round 3
// baseline (448.282 us; speedup 1.0000x reference)
//
#include <hip/hip_runtime.h>

// GraphSAGE 2-layer. N=40000, E=640000, 128 -> 512 (relu) -> 256.
// Round 10: XCD-sliced aggregation. Round-9 post-mortem: GEMMs fixed
// (dropped out of top-5); agg2 now dominates at 53 us with FETCH=161 MB
// vs a 20.5 MB hl array -- the random gather misses L2 because the full
// array can't fit one XCD's 4 MB L2. Fix: aggregation is columnwise-
// independent, so split cols into 8 slices (32 cols = 64 B/row for agg2,
// 16 cols = 32 B/row for agg1) and pin slice s to XCD s via round-robin
// dispatch (slice = blockIdx.x & 7, grid 625*8). Per-XCD gather working
// set: 2.56 MB (agg2) / 1.28 MB (agg1) -> L2-resident; 327 MB of gather
// reads move from the L2-miss path (3.9 TB/s) to L2 hits (34.5 TB/s).
// Quarter-wave (16 lanes) covers one 64 B row-slice -> 4 neighbors in
// flight per wave, x2 unrolled; shfl_xor butterfly reduce; no LDS.

#define N_NODES 40000
#define N_EDGES 640000
#define F_IN 128
#define F_HID 512
#define F_OUT 256
#define NB_SCAN 157  // ceil(40000/256)

typedef unsigned short ushort_t;
typedef __attribute__((ext_vector_type(8))) short bf16x8;
typedef __attribute__((ext_vector_type(4))) float floatx4;

__device__ __forceinline__ ushort_t f2bf(float f) {
  union { float f; unsigned int u; } x; x.f = f;
  unsigned int r = (x.u + 0x7FFFu + ((x.u >> 16) & 1u)) >> 16;  // RNE
  return (ushort_t)r;
}
__device__ __forceinline__ float bf2f(ushort_t u) {
  union { unsigned int u; float f; } x; x.u = ((unsigned int)u) << 16;
  return x.f;
}

// ---------------- CSR build ----------------
__global__ void deg_kernel(const int* __restrict__ ei, int* __restrict__ deg) {
  int e = blockIdx.x * blockDim.x + threadIdx.x;
  if (e < N_EDGES) atomicAdd(&deg[ei[N_EDGES + e]], 1);
}

__global__ void scanA_kernel(const int* __restrict__ deg, int* __restrict__ bsum) {
  __shared__ int sdata[256];
  int i = blockIdx.x * 256 + threadIdx.x;
  sdata[threadIdx.x] = (i < N_NODES) ? deg[i] : 0;
  __syncthreads();
  #pragma unroll
  for (int off = 128; off > 0; off >>= 1) {
    if (threadIdx.x < off) sdata[threadIdx.x] += sdata[threadIdx.x + off];
    __syncthreads();
  }
  if (threadIdx.x == 0) bsum[blockIdx.x] = sdata[0];
}

__global__ void scanB_kernel(const int* __restrict__ bsum, int* __restrict__ boff) {
  __shared__ int buf[2][256];
  int tid = threadIdx.x;
  int v = (tid < NB_SCAN) ? bsum[tid] : 0;
  buf[0][tid] = v;
  __syncthreads();
  int cur = 0;
  #pragma unroll
  for (int off = 1; off < 256; off <<= 1) {
    int val = buf[cur][tid];
    if (tid >= off) val += buf[cur][tid - off];
    buf[cur ^ 1][tid] = val;
    __syncthreads();
    cur ^= 1;
  }
  if (tid < NB_SCAN) boff[tid] = buf[cur][tid] - v;  // exclusive
}

__global__ void scanC_kernel(const int* __restrict__ deg, const int* __restrict__ boff,
                             int* __restrict__ rowptr, int* __restrict__ cursor) {
  __shared__ int buf[2][256];
  int tid = threadIdx.x;
  int i = blockIdx.x * 256 + tid;
  int v = (i < N_NODES) ? deg[i] : 0;
  buf[0][tid] = v;
  __syncthreads();
  int cur = 0;
  #pragma unroll
  for (int off = 1; off < 256; off <<= 1) {
    int val = buf[cur][tid];
    if (tid >= off) val += buf[cur][tid - off];
    buf[cur ^ 1][tid] = val;
    __syncthreads();
    cur ^= 1;
  }
  if (i < N_NODES) {
    int ex = boff[blockIdx.x] + buf[cur][tid] - v;
    rowptr[i] = ex;
    cursor[i] = ex;
    if (i == N_NODES - 1) rowptr[N_NODES] = ex + v;  // == E
  }
}

__global__ void fill_kernel(const int* __restrict__ ei, int* __restrict__ cursor,
                            int* __restrict__ col) {
  int e = blockIdx.x * blockDim.x + threadIdx.x;
  if (e < N_EDGES) {
    int d = ei[N_EDGES + e];
    int s = ei[e];
    int pos = atomicAdd(&cursor[d], 1);
    col[pos] = s;
  }
}

// ---------------- conversions ----------------
__global__ void cvt_x_kernel(const float* __restrict__ x, ushort_t* __restrict__ xb) {
  int i = blockIdx.x * blockDim.x + threadIdx.x;  // per float4
  const int n4 = (N_NODES * F_IN) / 4;
  if (i < n4) {
    float4 v = ((const float4*)x)[i];
    ushort4 o;
    o.x = f2bf(v.x); o.y = f2bf(v.y); o.z = f2bf(v.z); o.w = f2bf(v.w);
    ((ushort4*)xb)[i] = o;
  }
}

// Pack W (K x N, row-major) transposed+bf16 into the GEMM's per-lane order:
// element (n_global = rowoff+n, k_global = koff+k) lives at
//   Wp[((gg*(KT/32) + t)*4 + ni)*512 + (qk*16 + lm)*8 + j]
// where gg=n>>6, ni=(n>>4)&3, lm=n&15, c=kg>>3, t=c>>2, qk=c&3, j=kg&7.
// A wave's B-fragment load is then base + lane*16 (fully coalesced 1 KB).
__global__ void wp_kernel(const float* __restrict__ W, ushort_t* __restrict__ Wp,
                          int K, int N, int rowoff, int koff, int KT) {
  int i = blockIdx.x * blockDim.x + threadIdx.x;
  if (i < K * N) {
    int n = i / K, k = i - n * K;
    int ng = rowoff + n, kg = koff + k;
    int gg = ng >> 6, ni = (ng >> 4) & 3, lm = ng & 15;
    int c = kg >> 3, j = kg & 7, t = c >> 2, qk = c & 3;
    size_t dst = (((size_t)(gg * (KT / 32) + t) * 4 + ni) * 64 + qk * 16 + lm) * 8 + j;
    Wp[dst] = f2bf(W[(size_t)k * N + n]);
  }
}

__global__ void biascat_kernel(const float* __restrict__ b2, float* __restrict__ bc) {
  int i = threadIdx.x + blockIdx.x * blockDim.x;
  if (i < 512) bc[i] = (i < 256) ? 0.f : b2[i - 256];
}

// ---------------- aggregation (XCD-sliced) ----------------
// agg1: mean over neighbors of x_bf rows (128 cols bf16). 8 slices of
// 16 cols (32 B/row-slice). slice = blockIdx.x & 7 -> one XCD per slice
// (round-robin dispatch); per-XCD gather working set 1.28 MB -> L2-hot.
// Wave: 8 groups of 8 lanes; group g handles neighbor base+g; lane covers
// 2 cols (dword). Butterfly reduce over xor 8/16/32.
__global__ __launch_bounds__(256) void agg1_sliced(
    const ushort_t* __restrict__ Xb, ushort_t* __restrict__ Yb,
    const int* __restrict__ rowptr, const int* __restrict__ colidx) {
  const int slice = blockIdx.x & 7;
  const int g = blockIdx.x >> 3;            // 0..624
  const int wave = threadIdx.x >> 6, lane = threadIdx.x & 63;
  const int q = lane >> 3, lm = lane & 7;   // 8 groups of 8 lanes
  const int wid = g * 4 + wave;             // 0..2499
  const int colb = slice * 16 + lm * 2;     // dword col offset
  for (int i = 0; i < 16; ++i) {
    int n = wid * 16 + i;
    int s = rowptr[n], e = rowptr[n + 1];
    float s0 = 0.f, s1 = 0.f;
    int base = s;
    for (; base + q + 8 < e; base += 16) {  // 2 gathers in flight per lane
      int c0 = colidx[base + q];
      int c1 = colidx[base + q + 8];
      unsigned int v0 = *(const unsigned int*)(Xb + (size_t)c0 * F_IN + colb);
      unsigned int v1 = *(const unsigned int*)(Xb + (size_t)c1 * F_IN + colb);
      s0 += bf2f((ushort_t)(v0 & 0xffffu)) + bf2f((ushort_t)(v1 & 0xffffu));
      s1 += bf2f((ushort_t)(v0 >> 16)) + bf2f((ushort_t)(v1 >> 16));
    }
    for (; base + q < e; base += 8) {
      int c = colidx[base + q];
      unsigned int v = *(const unsigned int*)(Xb + (size_t)c * F_IN + colb);
      s0 += bf2f((ushort_t)(v & 0xffffu));
      s1 += bf2f((ushort_t)(v >> 16));
    }
    s0 += __shfl_xor(s0, 8);  s1 += __shfl_xor(s1, 8);
    s0 += __shfl_xor(s0, 16); s1 += __shfl_xor(s1, 16);
    s0 += __shfl_xor(s0, 32); s1 += __shfl_xor(s1, 32);
    if (q == 0) {
      float inv = 1.f / fmaxf((float)(e - s), 1.f);
      unsigned int o = (unsigned int)f2bf(s0 * inv) |
                       ((unsigned int)f2bf(s1 * inv) << 16);
      *(unsigned int*)(Yb + (size_t)n * F_IN + colb) = o;
    }
  }
}

// agg2: out = mean over neighbors of hl rows (256 cols bf16) + hr (fp32).
// 8 slices of 32 cols (64 B/row-slice = one cache line); per-XCD working
// set 2.56 MB -> L2-hot. Quarter-wave (16 lanes) per neighbor, 4 in
// parallel, x2 unrolled. Butterfly reduce over xor 16/32.
__global__ __launch_bounds__(256) void agg2_sliced(
    const ushort_t* __restrict__ hl, const float* __restrict__ hr,
    float* __restrict__ out,
    const int* __restrict__ rowptr, const int* __restrict__ colidx) {
  const int slice = blockIdx.x & 7;
  const int g = blockIdx.x >> 3;            // 0..624
  const int wave = threadIdx.x >> 6, lane = threadIdx.x & 63;
  const int q = lane >> 4, lm = lane & 15;  // 4 quarters of 16 lanes
  const int wid = g * 4 + wave;             // 0..2499
  const int colb = slice * 32 + lm * 2;     // dword col offset
  for (int i = 0; i < 16; ++i) {
    int n = wid * 16 + i;
    int s = rowptr[n], e = rowptr[n + 1];
    float s0 = 0.f, s1 = 0.f;
    int base = s;
    for (; base + q + 4 < e; base += 8) {   // 2 gathers in flight per lane
      int c0 = colidx[base + q];
      int c1 = colidx[base + q + 4];
      unsigned int v0 = *(const unsigned int*)(hl + (size_t)c0 * F_OUT + colb);
      unsigned int v1 = *(const unsigned int*)(hl + (size_t)c1 * F_OUT + colb);
      s0 += bf2f((ushort_t)(v0 & 0xffffu)) + bf2f((ushort_t)(v1 & 0xffffu));
      s1 += bf2f((ushort_t)(v0 >> 16)) + bf2f((ushort_t)(v1 >> 16));
    }
    for (; base + q < e; base += 4) {
      int c = colidx[base + q];
      unsigned int v = *(const unsigned int*)(hl + (size_t)c * F_OUT + colb);
      s0 += bf2f((ushort_t)(v & 0xffffu));
      s1 += bf2f((ushort_t)(v >> 16));
    }
    s0 += __shfl_xor(s0, 16); s1 += __shfl_xor(s1, 16);
    s0 += __shfl_xor(s0, 32); s1 += __shfl_xor(s1, 32);
    if (q == 0) {
      float inv = 1.f / fmaxf((float)(e - s), 1.f);
      float2 hrv = *(const float2*)(hr + (size_t)n * F_OUT + colb);
      float2 o;
      o.x = s0 * inv + hrv.x;
      o.y = s1 * inv + hrv.y;
      *(float2*)(out + (size_t)n * F_OUT + colb) = o;
    }
  }
}

// ---------------- bf16 MFMA GEMM ----------------
// C[M, 512] = Acat[M, KT] @ Wcat[KT, 512] (+bias)(relu). Acat = [A0 | A1]
// when TWOPAIR (K0 = KT/2 each). Wp pre-packed per-lane (see wp_kernel).
// BM=64, BN=256, 256 threads (4 waves, wave w owns cols w*64..w*64+63).
// A-panel staged in K-halves of 256 (Apan 32 KB -> 4 blocks/CU, 16 waves/CU);
// layer 2 (KT=512) re-stages once mid-loop. XOR swizzle on ds_write/ds_read.
// B: register double-buffer, coalesced 1 KB wave-loads, no barriers in K-loop.
// Swapped-operand MFMA: acc[mi][ni] = mfma(bv, av, acc) -> lane's 4 acc regs
// are 4 consecutive output cols of one row -> vector epilogue stores.
// SPLITOUT: N-block 0 -> Cb bf16 [M][256], N-block 1 -> Cf fp32 [M][256].
template <bool TWOPAIR, bool RELU, bool BIAS, bool OUT_BF16, bool SPLITOUT, int KT>
__global__ __launch_bounds__(256) void gemm_mfma(
    const ushort_t* __restrict__ A0, const ushort_t* __restrict__ A1,
    const ushort_t* __restrict__ Wp, const float* __restrict__ bias,
    float* __restrict__ Cf, ushort_t* __restrict__ Cb, int M) {
  const int KH = (KT > 256) ? 256 : KT;  // staged K extent: 32 KB LDS
  const int NH = KT / KH;                // 1 (layer 1) or 2 (layer 2)
  const int NKH = KH / 8;                // 16B chunks per row per stage = 32
  __shared__ ushort_t Apan[64 * KH];
  const int tid = threadIdx.x;
  const int wave = tid >> 6, lane = tid & 63;
  const int lm = lane & 15, qk = lane >> 4;
  const int bn = blockIdx.x * 256;   // N-block fastest -> sibling blocks share A
  const int bm = blockIdx.y * 64;    // 625 * 64 = 40000 exactly, no tail
  const int K0 = TWOPAIR ? KT / 2 : KT;
  const int K0c = K0 / 8;

  // per-wave B base: (g,t) blocks of 4 KB, ni sub-blocks of 1 KB
  const ushort_t* wpg = Wp + (size_t)(blockIdx.x * 4 + wave) * (KT / 32) * 2048;

  auto stageA = [&](int h) {
    #pragma unroll
    for (int q = 0; q < (64 * NKH) / 256; ++q) {
      int c = tid + q * 256;
      int lc = c & (NKH - 1);
      int row = c / NKH;
      int kc = h * NKH + lc;
      const ushort_t* src = (TWOPAIR && kc >= K0c)
          ? A1 + (size_t)(bm + row) * K0 + (kc - K0c) * 8
          : A0 + (size_t)(bm + row) * K0 + kc * 8;
      bf16x8 v = *(const bf16x8*)src;
      size_t off = ((size_t)(lc * 64 + row) * 16) ^ (size_t)((lc & 7) << 4);
      *(bf16x8*)((char*)Apan + off) = v;
    }
  };

  stageA(0);
  bf16x8 bvA[4], bvB[4];
  #pragma unroll
  for (int ni = 0; ni < 4; ++ni)
    bvA[ni] = *(const bf16x8*)(wpg + (size_t)ni * 512 + lane * 8);  // t=0
  __syncthreads();  // A half 0 visible

  floatx4 acc[4][4] = {};
  #pragma unroll 1
  for (int h = 0; h < NH; ++h) {
    if (h) {
      __syncthreads();   // everyone done reading previous half
      stageA(h);
      __syncthreads();   // new half visible (B prefetch stays in flight)
    }
    #pragma unroll 1
    for (int kb = 0; kb < KH; kb += 64) {
      const int t0 = (h * KH + kb) / 32;
      // prefetch second half-tile of this iteration (t0+1)
      #pragma unroll
      for (int ni = 0; ni < 4; ++ni)
        bvB[ni] = *(const bf16x8*)(wpg + ((size_t)(t0 + 1) * 4 + ni) * 512 + lane * 8);

      bf16x8 av[4];
      const int kc0 = kb / 8 + qk;
      #pragma unroll
      for (int mi = 0; mi < 4; ++mi) {
        size_t off = ((size_t)(kc0 * 64 + mi * 16 + lm) * 16) ^ (size_t)((kc0 & 7) << 4);
        av[mi] = *(const bf16x8*)((char*)Apan + off);
      }
      #pragma unroll
      for (int mi = 0; mi < 4; ++mi)
        #pragma unroll
        for (int ni = 0; ni < 4; ++ni)
          acc[mi][ni] = __builtin_amdgcn_mfma_f32_16x16x32_bf16(
              bvA[ni], av[mi], acc[mi][ni], 0, 0, 0);  // swapped operands

      // prefetch first half-tile of NEXT iteration (t0+2), uniform branch
      if (h * KH + kb + 64 < KT) {
        #pragma unroll
        for (int ni = 0; ni < 4; ++ni)
          bvA[ni] = *(const bf16x8*)(wpg + ((size_t)(t0 + 2) * 4 + ni) * 512 + lane * 8);
      }

      const int kc1 = kb / 8 + 4 + qk;
      #pragma unroll
      for (int mi = 0; mi < 4; ++mi) {
        size_t off = ((size_t)(kc1 * 64 + mi * 16 + lm) * 16) ^ (size_t)((kc1 & 7) << 4);
        av[mi] = *(const bf16x8*)((char*)Apan + off);
      }
      #pragma unroll
      for (int mi = 0; mi < 4; ++mi)
        #pragma unroll
        for (int ni = 0; ni < 4; ++ni)
          acc[mi][ni] = __builtin_amdgcn_mfma_f32_16x16x32_bf16(
              bvB[ni], av[mi], acc[mi][ni], 0, 0, 0);
    }
  }

  // ---- epilogue: row = bm + mi*16 + lm, cols = bn + wave*64 + ni*16 + qk*4 ----
  #pragma unroll
  for (int ni = 0; ni < 4; ++ni) {
    int colg = bn + wave * 64 + ni * 16 + qk * 4;
    float4 b4 = {0.f, 0.f, 0.f, 0.f};
    if (BIAS) b4 = *(const float4*)&bias[colg];
    #pragma unroll
    for (int mi = 0; mi < 4; ++mi) {
      int rowg = bm + mi * 16 + lm;
      float v0 = acc[mi][ni][0] + b4.x;
      float v1 = acc[mi][ni][1] + b4.y;
      float v2 = acc[mi][ni][2] + b4.z;
      float v3 = acc[mi][ni][3] + b4.w;
      if (RELU) {
        v0 = fmaxf(v0, 0.f); v1 = fmaxf(v1, 0.f);
        v2 = fmaxf(v2, 0.f); v3 = fmaxf(v3, 0.f);
      }
      if (SPLITOUT) {
        if (colg < 256) {
          ushort4 o = {f2bf(v0), f2bf(v1), f2bf(v2), f2bf(v3)};
          *(ushort4*)&Cb[(size_t)rowg * 256 + colg] = o;
        } else {
          float4 o = {v0, v1, v2, v3};
          *(float4*)&Cf[(size_t)rowg * 256 + (colg - 256)] = o;
        }
      } else if (OUT_BF16) {
        ushort4 o = {f2bf(v0), f2bf(v1), f2bf(v2), f2bf(v3)};
        *(ushort4*)&Cb[(size_t)rowg * 512 + colg] = o;
      } else {
        float4 o = {v0, v1, v2, v3};
        *(float4*)&Cf[(size_t)rowg * 512 + colg] = o;
      }
    }
  }
}

extern "C" void kernel_launch(void* const* d_in, const int* in_sizes, int n_in,
                              void* d_out, int out_size, void* d_ws, size_t ws_size,
                              hipStream_t stream) {
  const float* x = (const float*)d_in[0];
  const int* ei = (const int*)d_in[1];  // int32 per harness, [2][E]
  const float* W1l = (const float*)d_in[2];
  const float* b1 = (const float*)d_in[3];
  const float* W1r = (const float*)d_in[4];
  const float* W2l = (const float*)d_in[5];
  const float* b2 = (const float*)d_in[6];
  const float* W2r = (const float*)d_in[7];
  float* out = (float*)d_out;

  char* ws = (char*)d_ws;
  size_t off = 0;
  auto alloc = [&](size_t bytes) {
    void* p = ws + off;
    off = (off + bytes + 255) & ~(size_t)255;
    return p;
  };
  int* deg = (int*)alloc((size_t)N_NODES * 4);
  int* rowptr = (int*)alloc((size_t)(N_NODES + 1) * 4);
  int* cursor = (int*)alloc((size_t)N_NODES * 4);
  int* col = (int*)alloc((size_t)N_EDGES * 4);
  int* bsum = (int*)alloc((size_t)NB_SCAN * 4);
  int* boff = (int*)alloc((size_t)NB_SCAN * 4);
  ushort_t* x_bf = (ushort_t*)alloc((size_t)N_NODES * F_IN * 2);
  ushort_t* aggx_bf = (ushort_t*)alloc((size_t)N_NODES * F_IN * 2);
  ushort_t* h_bf = (ushort_t*)alloc((size_t)N_NODES * F_HID * 2);
  ushort_t* hl_bf = (ushort_t*)alloc((size_t)N_NODES * F_OUT * 2);  // h@W2l, bf16
  float* hr = (float*)alloc((size_t)N_NODES * F_OUT * 4);           // h@W2r + b2
  ushort_t* Wp1 = (ushort_t*)alloc((size_t)512 * 256 * 2);   // packed [W1l^T|W1r^T]
  ushort_t* Wp2 = (ushort_t*)alloc((size_t)512 * 512 * 2);   // packed [W2l|W2r]
  float* biascat = (float*)alloc(512 * 4);

  // CSR build
  hipMemsetAsync(deg, 0, (size_t)N_NODES * 4, stream);
  deg_kernel<<<(N_EDGES + 255) / 256, 256, 0, stream>>>(ei, deg);
  scanA_kernel<<<NB_SCAN, 256, 0, stream>>>(deg, bsum);
  scanB_kernel<<<1, 256, 0, stream>>>(bsum, boff);
  scanC_kernel<<<NB_SCAN, 256, 0, stream>>>(deg, boff, rowptr, cursor);
  fill_kernel<<<(N_EDGES + 255) / 256, 256, 0, stream>>>(ei, cursor, col);

  // Conversions (independent of CSR)
  cvt_x_kernel<<<(N_NODES * F_IN / 4 + 255) / 256, 256, 0, stream>>>(x, x_bf);
  // layer 1: K-concat (koff 0 / 128), KT=256
  wp_kernel<<<(F_IN * F_HID + 255) / 256, 256, 0, stream>>>(W1l, Wp1, 128, 512, 0, 0, 256);
  wp_kernel<<<(F_IN * F_HID + 255) / 256, 256, 0, stream>>>(W1r, Wp1, 128, 512, 0, 128, 256);
  // layer 2: N-concat (rowoff 0 / 256), KT=512
  wp_kernel<<<(F_HID * F_OUT + 255) / 256, 256, 0, stream>>>(W2l, Wp2, 512, 256, 0, 0, 512);
  wp_kernel<<<(F_HID * F_OUT + 255) / 256, 256, 0, stream>>>(W2r, Wp2, 512, 256, 256, 0, 512);
  biascat_kernel<<<2, 256, 0, stream>>>(b2, biascat);

  // Layer 1: aggx_bf = mean-agg(x_bf); h_bf = relu([aggx|x] @ [W1l;W1r] + b1)
  agg1_sliced<<<5000, 256, 0, stream>>>(x_bf, aggx_bf, rowptr, col);
  gemm_mfma<true, true, true, true, false, 256>
      <<<dim3(2, N_NODES / 64), 256, 0, stream>>>(
          aggx_bf, x_bf, Wp1, b1, nullptr, h_bf, N_NODES);

  // Layer 2 fused: [hl_bf | hr] = h_bf @ [W2l|W2r] + [0|b2], split outputs
  gemm_mfma<false, false, true, false, true, 512>
      <<<dim3(2, N_NODES / 64), 256, 0, stream>>>(
          h_bf, nullptr, Wp2, biascat, hr, hl_bf, N_NODES);
  // out = mean-agg(hl_bf) + hr
  agg2_sliced<<<5000, 256, 0, stream>>>(hl_bf, hr, out, rowptr, col);
}

// Round 4
// 306.815 us; speedup vs baseline: 1.4611x; 1.4611x over previous
//
#include <hip/hip_runtime.h>

// GraphSAGE 2-layer. N=40000, E=640000, 128 -> 512 (relu) -> 256.
// Round 11: revert the XCD-sliced aggregation (round-10 regression: same
// FETCH, 2.5x time -- the gather is latency/MLP-bound on the L3-hit path,
// not L2-capacity-bound; slicing wrecked coalescing and in-flight count).
// Back to round-9 aggregation (full-row coalesced reads, node per block),
// with the neighbor loop unrolled x8 (8 independent gathers in flight per
// thread, was 4) and the hr streaming load hoisted ahead of the gather
// loop. GEMMs / CSR / packing unchanged from round-9 (307.6 us total).

#define N_NODES 40000
#define N_EDGES 640000
#define F_IN 128
#define F_HID 512
#define F_OUT 256
#define NB_SCAN 157  // ceil(40000/256)

typedef unsigned short ushort_t;
typedef __attribute__((ext_vector_type(8))) short bf16x8;
typedef __attribute__((ext_vector_type(4))) float floatx4;

__device__ __forceinline__ ushort_t f2bf(float f) {
  union { float f; unsigned int u; } x; x.f = f;
  unsigned int r = (x.u + 0x7FFFu + ((x.u >> 16) & 1u)) >> 16;  // RNE
  return (ushort_t)r;
}
__device__ __forceinline__ float bf2f(ushort_t u) {
  union { unsigned int u; float f; } x; x.u = ((unsigned int)u) << 16;
  return x.f;
}

// ---------------- CSR build ----------------
__global__ void deg_kernel(const int* __restrict__ ei, int* __restrict__ deg) {
  int e = blockIdx.x * blockDim.x + threadIdx.x;
  if (e < N_EDGES) atomicAdd(&deg[ei[N_EDGES + e]], 1);
}

__global__ void scanA_kernel(const int* __restrict__ deg, int* __restrict__ bsum) {
  __shared__ int sdata[256];
  int i = blockIdx.x * 256 + threadIdx.x;
  sdata[threadIdx.x] = (i < N_NODES) ? deg[i] : 0;
  __syncthreads();
  #pragma unroll
  for (int off = 128; off > 0; off >>= 1) {
    if (threadIdx.x < off) sdata[threadIdx.x] += sdata[threadIdx.x + off];
    __syncthreads();
  }
  if (threadIdx.x == 0) bsum[blockIdx.x] = sdata[0];
}

__global__ void scanB_kernel(const int* __restrict__ bsum, int* __restrict__ boff) {
  __shared__ int buf[2][256];
  int tid = threadIdx.x;
  int v = (tid < NB_SCAN) ? bsum[tid] : 0;
  buf[0][tid] = v;
  __syncthreads();
  int cur = 0;
  #pragma unroll
  for (int off = 1; off < 256; off <<= 1) {
    int val = buf[cur][tid];
    if (tid >= off) val += buf[cur][tid - off];
    buf[cur ^ 1][tid] = val;
    __syncthreads();
    cur ^= 1;
  }
  if (tid < NB_SCAN) boff[tid] = buf[cur][tid] - v;  // exclusive
}

__global__ void scanC_kernel(const int* __restrict__ deg, const int* __restrict__ boff,
                             int* __restrict__ rowptr, int* __restrict__ cursor) {
  __shared__ int buf[2][256];
  int tid = threadIdx.x;
  int i = blockIdx.x * 256 + tid;
  int v = (i < N_NODES) ? deg[i] : 0;
  buf[0][tid] = v;
  __syncthreads();
  int cur = 0;
  #pragma unroll
  for (int off = 1; off < 256; off <<= 1) {
    int val = buf[cur][tid];
    if (tid >= off) val += buf[cur][tid - off];
    buf[cur ^ 1][tid] = val;
    __syncthreads();
    cur ^= 1;
  }
  if (i < N_NODES) {
    int ex = boff[blockIdx.x] + buf[cur][tid] - v;
    rowptr[i] = ex;
    cursor[i] = ex;
    if (i == N_NODES - 1) rowptr[N_NODES] = ex + v;  // == E
  }
}

__global__ void fill_kernel(const int* __restrict__ ei, int* __restrict__ cursor,
                            int* __restrict__ col) {
  int e = blockIdx.x * blockDim.x + threadIdx.x;
  if (e < N_EDGES) {
    int d = ei[N_EDGES + e];
    int s = ei[e];
    int pos = atomicAdd(&cursor[d], 1);
    col[pos] = s;
  }
}

// ---------------- conversions ----------------
__global__ void cvt_x_kernel(const float* __restrict__ x, ushort_t* __restrict__ xb) {
  int i = blockIdx.x * blockDim.x + threadIdx.x;  // per float4
  const int n4 = (N_NODES * F_IN) / 4;
  if (i < n4) {
    float4 v = ((const float4*)x)[i];
    ushort4 o;
    o.x = f2bf(v.x); o.y = f2bf(v.y); o.z = f2bf(v.z); o.w = f2bf(v.w);
    ((ushort4*)xb)[i] = o;
  }
}

// Pack W (K x N, row-major) transposed+bf16 into the GEMM's per-lane order:
// element (n_global = rowoff+n, k_global = koff+k) lives at
//   Wp[((gg*(KT/32) + t)*4 + ni)*512 + (qk*16 + lm)*8 + j]
// where gg=n>>6, ni=(n>>4)&3, lm=n&15, c=kg>>3, t=c>>2, qk=c&3, j=kg&7.
// A wave's B-fragment load is then base + lane*16 (fully coalesced 1 KB).
__global__ void wp_kernel(const float* __restrict__ W, ushort_t* __restrict__ Wp,
                          int K, int N, int rowoff, int koff, int KT) {
  int i = blockIdx.x * blockDim.x + threadIdx.x;
  if (i < K * N) {
    int n = i / K, k = i - n * K;
    int ng = rowoff + n, kg = koff + k;
    int gg = ng >> 6, ni = (ng >> 4) & 3, lm = ng & 15;
    int c = kg >> 3, j = kg & 7, t = c >> 2, qk = c & 3;
    size_t dst = (((size_t)(gg * (KT / 32) + t) * 4 + ni) * 64 + qk * 16 + lm) * 8 + j;
    Wp[dst] = f2bf(W[(size_t)k * N + n]);
  }
}

__global__ void biascat_kernel(const float* __restrict__ b2, float* __restrict__ bc) {
  int i = threadIdx.x + blockIdx.x * blockDim.x;
  if (i < 512) bc[i] = (i < 256) ? 0.f : b2[i - 256];
}

// ---------------- aggregation ----------------
// Node per block, full-row coalesced gathers, 8 loads in flight per thread.
__global__ void agg1_kernel(const ushort_t* __restrict__ Xb, ushort_t* __restrict__ Yb,
                            const int* __restrict__ rowptr, const int* __restrict__ colidx) {
  __shared__ int cols[64];
  int n = blockIdx.x, f = threadIdx.x;
  int s = rowptr[n], e = rowptr[n + 1];
  float s0 = 0.f, s1 = 0.f;
  for (int base = s; base < e; base += 64) {
    int cnt = min(64, e - base);
    __syncthreads();
    if (f < cnt) cols[f] = colidx[base + f];
    __syncthreads();
    int j = 0;
    for (; j + 8 <= cnt; j += 8) {  // 8 gathers in flight
      unsigned int v[8];
      #pragma unroll
      for (int u = 0; u < 8; ++u)
        v[u] = *(const unsigned int*)(Xb + (size_t)cols[j + u] * F_IN + 2 * f);
      #pragma unroll
      for (int u = 0; u < 8; ++u) {
        s0 += bf2f((ushort_t)(v[u] & 0xffffu));
        s1 += bf2f((ushort_t)(v[u] >> 16));
      }
    }
    for (; j < cnt; ++j) {
      unsigned int v = *(const unsigned int*)(Xb + (size_t)cols[j] * F_IN + 2 * f);
      s0 += bf2f((ushort_t)(v & 0xffffu));
      s1 += bf2f((ushort_t)(v >> 16));
    }
  }
  float inv = 1.f / fmaxf((float)(e - s), 1.f);
  unsigned int o = (unsigned int)f2bf(s0 * inv) | ((unsigned int)f2bf(s1 * inv) << 16);
  *(unsigned int*)(Yb + (size_t)n * F_IN + 2 * f) = o;
}

__global__ void agg2_kernel(const ushort_t* __restrict__ hl, const float* __restrict__ hr,
                            float* __restrict__ out,
                            const int* __restrict__ rowptr, const int* __restrict__ colidx) {
  __shared__ int cols[128];
  int n = blockIdx.x, f = threadIdx.x;
  int s = rowptr[n], e = rowptr[n + 1];
  float2 hrv = *(const float2*)(hr + (size_t)n * F_OUT + 2 * f);  // hoisted stream
  float s0 = 0.f, s1 = 0.f;
  for (int base = s; base < e; base += 128) {
    int cnt = min(128, e - base);
    __syncthreads();
    if (f < cnt) cols[f] = colidx[base + f];
    __syncthreads();
    int j = 0;
    for (; j + 8 <= cnt; j += 8) {  // 8 gathers in flight
      unsigned int v[8];
      #pragma unroll
      for (int u = 0; u < 8; ++u)
        v[u] = *(const unsigned int*)(hl + (size_t)cols[j + u] * F_OUT + 2 * f);
      #pragma unroll
      for (int u = 0; u < 8; ++u) {
        s0 += bf2f((ushort_t)(v[u] & 0xffffu));
        s1 += bf2f((ushort_t)(v[u] >> 16));
      }
    }
    for (; j < cnt; ++j) {
      unsigned int v = *(const unsigned int*)(hl + (size_t)cols[j] * F_OUT + 2 * f);
      s0 += bf2f((ushort_t)(v & 0xffffu));
      s1 += bf2f((ushort_t)(v >> 16));
    }
  }
  float inv = 1.f / fmaxf((float)(e - s), 1.f);
  float2 o;
  o.x = s0 * inv + hrv.x;
  o.y = s1 * inv + hrv.y;
  *(float2*)(out + (size_t)n * F_OUT + 2 * f) = o;
}

// ---------------- bf16 MFMA GEMM ----------------
// C[M, 512] = Acat[M, KT] @ Wcat[KT, 512] (+bias)(relu). Acat = [A0 | A1]
// when TWOPAIR (K0 = KT/2 each). Wp pre-packed per-lane (see wp_kernel).
// BM=64, BN=256, 256 threads (4 waves, wave w owns cols w*64..w*64+63).
// A-panel staged in K-halves of 256 (Apan 32 KB -> 4 blocks/CU, 16 waves/CU);
// layer 2 (KT=512) re-stages once mid-loop. XOR swizzle on ds_write/ds_read.
// B: register double-buffer, coalesced 1 KB wave-loads, no barriers in K-loop.
// Swapped-operand MFMA: acc[mi][ni] = mfma(bv, av, acc) -> lane's 4 acc regs
// are 4 consecutive output cols of one row -> vector epilogue stores.
// SPLITOUT: N-block 0 -> Cb bf16 [M][256], N-block 1 -> Cf fp32 [M][256].
template <bool TWOPAIR, bool RELU, bool BIAS, bool OUT_BF16, bool SPLITOUT, int KT>
__global__ __launch_bounds__(256) void gemm_mfma(
    const ushort_t* __restrict__ A0, const ushort_t* __restrict__ A1,
    const ushort_t* __restrict__ Wp, const float* __restrict__ bias,
    float* __restrict__ Cf, ushort_t* __restrict__ Cb, int M) {
  const int KH = (KT > 256) ? 256 : KT;  // staged K extent: 32 KB LDS
  const int NH = KT / KH;                // 1 (layer 1) or 2 (layer 2)
  const int NKH = KH / 8;                // 16B chunks per row per stage = 32
  __shared__ ushort_t Apan[64 * KH];
  const int tid = threadIdx.x;
  const int wave = tid >> 6, lane = tid & 63;
  const int lm = lane & 15, qk = lane >> 4;
  const int bn = blockIdx.x * 256;   // N-block fastest -> sibling blocks share A
  const int bm = blockIdx.y * 64;    // 625 * 64 = 40000 exactly, no tail
  const int K0 = TWOPAIR ? KT / 2 : KT;
  const int K0c = K0 / 8;

  // per-wave B base: (g,t) blocks of 4 KB, ni sub-blocks of 1 KB
  const ushort_t* wpg = Wp + (size_t)(blockIdx.x * 4 + wave) * (KT / 32) * 2048;

  auto stageA = [&](int h) {
    #pragma unroll
    for (int q = 0; q < (64 * NKH) / 256; ++q) {
      int c = tid + q * 256;
      int lc = c & (NKH - 1);
      int row = c / NKH;
      int kc = h * NKH + lc;
      const ushort_t* src = (TWOPAIR && kc >= K0c)
          ? A1 + (size_t)(bm + row) * K0 + (kc - K0c) * 8
          : A0 + (size_t)(bm + row) * K0 + kc * 8;
      bf16x8 v = *(const bf16x8*)src;
      size_t off = ((size_t)(lc * 64 + row) * 16) ^ (size_t)((lc & 7) << 4);
      *(bf16x8*)((char*)Apan + off) = v;
    }
  };

  stageA(0);
  bf16x8 bvA[4], bvB[4];
  #pragma unroll
  for (int ni = 0; ni < 4; ++ni)
    bvA[ni] = *(const bf16x8*)(wpg + (size_t)ni * 512 + lane * 8);  // t=0
  __syncthreads();  // A half 0 visible

  floatx4 acc[4][4] = {};
  #pragma unroll 1
  for (int h = 0; h < NH; ++h) {
    if (h) {
      __syncthreads();   // everyone done reading previous half
      stageA(h);
      __syncthreads();   // new half visible (B prefetch stays in flight)
    }
    #pragma unroll 1
    for (int kb = 0; kb < KH; kb += 64) {
      const int t0 = (h * KH + kb) / 32;
      // prefetch second half-tile of this iteration (t0+1)
      #pragma unroll
      for (int ni = 0; ni < 4; ++ni)
        bvB[ni] = *(const bf16x8*)(wpg + ((size_t)(t0 + 1) * 4 + ni) * 512 + lane * 8);

      bf16x8 av[4];
      const int kc0 = kb / 8 + qk;
      #pragma unroll
      for (int mi = 0; mi < 4; ++mi) {
        size_t off = ((size_t)(kc0 * 64 + mi * 16 + lm) * 16) ^ (size_t)((kc0 & 7) << 4);
        av[mi] = *(const bf16x8*)((char*)Apan + off);
      }
      #pragma unroll
      for (int mi = 0; mi < 4; ++mi)
        #pragma unroll
        for (int ni = 0; ni < 4; ++ni)
          acc[mi][ni] = __builtin_amdgcn_mfma_f32_16x16x32_bf16(
              bvA[ni], av[mi], acc[mi][ni], 0, 0, 0);  // swapped operands

      // prefetch first half-tile of NEXT iteration (t0+2), uniform branch
      if (h * KH + kb + 64 < KT) {
        #pragma unroll
        for (int ni = 0; ni < 4; ++ni)
          bvA[ni] = *(const bf16x8*)(wpg + ((size_t)(t0 + 2) * 4 + ni) * 512 + lane * 8);
      }

      const int kc1 = kb / 8 + 4 + qk;
      #pragma unroll
      for (int mi = 0; mi < 4; ++mi) {
        size_t off = ((size_t)(kc1 * 64 + mi * 16 + lm) * 16) ^ (size_t)((kc1 & 7) << 4);
        av[mi] = *(const bf16x8*)((char*)Apan + off);
      }
      #pragma unroll
      for (int mi = 0; mi < 4; ++mi)
        #pragma unroll
        for (int ni = 0; ni < 4; ++ni)
          acc[mi][ni] = __builtin_amdgcn_mfma_f32_16x16x32_bf16(
              bvB[ni], av[mi], acc[mi][ni], 0, 0, 0);
    }
  }

  // ---- epilogue: row = bm + mi*16 + lm, cols = bn + wave*64 + ni*16 + qk*4 ----
  #pragma unroll
  for (int ni = 0; ni < 4; ++ni) {
    int colg = bn + wave * 64 + ni * 16 + qk * 4;
    float4 b4 = {0.f, 0.f, 0.f, 0.f};
    if (BIAS) b4 = *(const float4*)&bias[colg];
    #pragma unroll
    for (int mi = 0; mi < 4; ++mi) {
      int rowg = bm + mi * 16 + lm;
      float v0 = acc[mi][ni][0] + b4.x;
      float v1 = acc[mi][ni][1] + b4.y;
      float v2 = acc[mi][ni][2] + b4.z;
      float v3 = acc[mi][ni][3] + b4.w;
      if (RELU) {
        v0 = fmaxf(v0, 0.f); v1 = fmaxf(v1, 0.f);
        v2 = fmaxf(v2, 0.f); v3 = fmaxf(v3, 0.f);
      }
      if (SPLITOUT) {
        if (colg < 256) {
          ushort4 o = {f2bf(v0), f2bf(v1), f2bf(v2), f2bf(v3)};
          *(ushort4*)&Cb[(size_t)rowg * 256 + colg] = o;
        } else {
          float4 o = {v0, v1, v2, v3};
          *(float4*)&Cf[(size_t)rowg * 256 + (colg - 256)] = o;
        }
      } else if (OUT_BF16) {
        ushort4 o = {f2bf(v0), f2bf(v1), f2bf(v2), f2bf(v3)};
        *(ushort4*)&Cb[(size_t)rowg * 512 + colg] = o;
      } else {
        float4 o = {v0, v1, v2, v3};
        *(float4*)&Cf[(size_t)rowg * 512 + colg] = o;
      }
    }
  }
}

extern "C" void kernel_launch(void* const* d_in, const int* in_sizes, int n_in,
                              void* d_out, int out_size, void* d_ws, size_t ws_size,
                              hipStream_t stream) {
  const float* x = (const float*)d_in[0];
  const int* ei = (const int*)d_in[1];  // int32 per harness, [2][E]
  const float* W1l = (const float*)d_in[2];
  const float* b1 = (const float*)d_in[3];
  const float* W1r = (const float*)d_in[4];
  const float* W2l = (const float*)d_in[5];
  const float* b2 = (const float*)d_in[6];
  const float* W2r = (const float*)d_in[7];
  float* out = (float*)d_out;

  char* ws = (char*)d_ws;
  size_t off = 0;
  auto alloc = [&](size_t bytes) {
    void* p = ws + off;
    off = (off + bytes + 255) & ~(size_t)255;
    return p;
  };
  int* deg = (int*)alloc((size_t)N_NODES * 4);
  int* rowptr = (int*)alloc((size_t)(N_NODES + 1) * 4);
  int* cursor = (int*)alloc((size_t)N_NODES * 4);
  int* col = (int*)alloc((size_t)N_EDGES * 4);
  int* bsum = (int*)alloc((size_t)NB_SCAN * 4);
  int* boff = (int*)alloc((size_t)NB_SCAN * 4);
  ushort_t* x_bf = (ushort_t*)alloc((size_t)N_NODES * F_IN * 2);
  ushort_t* aggx_bf = (ushort_t*)alloc((size_t)N_NODES * F_IN * 2);
  ushort_t* h_bf = (ushort_t*)alloc((size_t)N_NODES * F_HID * 2);
  ushort_t* hl_bf = (ushort_t*)alloc((size_t)N_NODES * F_OUT * 2);  // h@W2l, bf16
  float* hr = (float*)alloc((size_t)N_NODES * F_OUT * 4);           // h@W2r + b2
  ushort_t* Wp1 = (ushort_t*)alloc((size_t)512 * 256 * 2);   // packed [W1l^T|W1r^T]
  ushort_t* Wp2 = (ushort_t*)alloc((size_t)512 * 512 * 2);   // packed [W2l|W2r]
  float* biascat = (float*)alloc(512 * 4);

  // CSR build
  hipMemsetAsync(deg, 0, (size_t)N_NODES * 4, stream);
  deg_kernel<<<(N_EDGES + 255) / 256, 256, 0, stream>>>(ei, deg);
  scanA_kernel<<<NB_SCAN, 256, 0, stream>>>(deg, bsum);
  scanB_kernel<<<1, 256, 0, stream>>>(bsum, boff);
  scanC_kernel<<<NB_SCAN, 256, 0, stream>>>(deg, boff, rowptr, cursor);
  fill_kernel<<<(N_EDGES + 255) / 256, 256, 0, stream>>>(ei, cursor, col);

  // Conversions (independent of CSR)
  cvt_x_kernel<<<(N_NODES * F_IN / 4 + 255) / 256, 256, 0, stream>>>(x, x_bf);
  // layer 1: K-concat (koff 0 / 128), KT=256
  wp_kernel<<<(F_IN * F_HID + 255) / 256, 256, 0, stream>>>(W1l, Wp1, 128, 512, 0, 0, 256);
  wp_kernel<<<(F_IN * F_HID + 255) / 256, 256, 0, stream>>>(W1r, Wp1, 128, 512, 0, 128, 256);
  // layer 2: N-concat (rowoff 0 / 256), KT=512
  wp_kernel<<<(F_HID * F_OUT + 255) / 256, 256, 0, stream>>>(W2l, Wp2, 512, 256, 0, 0, 512);
  wp_kernel<<<(F_HID * F_OUT + 255) / 256, 256, 0, stream>>>(W2r, Wp2, 512, 256, 256, 0, 512);
  biascat_kernel<<<2, 256, 0, stream>>>(b2, biascat);

  // Layer 1: aggx_bf = mean-agg(x_bf); h_bf = relu([aggx|x] @ [W1l;W1r] + b1)
  agg1_kernel<<<N_NODES, 64, 0, stream>>>(x_bf, aggx_bf, rowptr, col);
  gemm_mfma<true, true, true, true, false, 256>
      <<<dim3(2, N_NODES / 64), 256, 0, stream>>>(
          aggx_bf, x_bf, Wp1, b1, nullptr, h_bf, N_NODES);

  // Layer 2 fused: [hl_bf | hr] = h_bf @ [W2l|W2r] + [0|b2], split outputs
  gemm_mfma<false, false, true, false, true, 512>
      <<<dim3(2, N_NODES / 64), 256, 0, stream>>>(
          h_bf, nullptr, Wp2, biascat, hr, hl_bf, N_NODES);
  // out = mean-agg(hl_bf) + hr
  agg2_kernel<<<N_NODES, 128, 0, stream>>>(hl_bf, hr, out, rowptr, col);
}

// Round 5
// 297.639 us; speedup vs baseline: 1.5061x; 1.0308x over previous
//
#include <hip/hip_runtime.h>

// GraphSAGE 2-layer. N=40000, E=640000, 128 -> 512 (relu) -> 256.
// Round 12: (1) single-N-block GEMMs -- 512 threads / 8 waves, wave w owns
// cols 64w..64w+63; grid 625. Kills the duplicate A-panel fetch (layer-2
// read h 2x = 82 MB, layer-1 read aggx|x 2x = 40 MB -> halved, ~-15 us).
// Occupancy unchanged: VGPR 96 -> 5 waves/SIMD -> 2 blocks x 8 waves =
// 16 waves/CU (same as 4 x 4 before); LDS 2 x 32 KB.
// (2) prep fusion: cvt_x + 4x wp + biascat + deg in ONE kernel branched on
// blockIdx range (16 -> 9 launches, ~-10 us of launch/drain tax).
// agg kernels unchanged from round-11 (agg2 is fetch-BW-bound at ~3.9 TB/s
// on the random-512B-gather path; declared near-ceiling after 3 variants
// converged on identical FETCH/time).

#define N_NODES 40000
#define N_EDGES 640000
#define F_IN 128
#define F_HID 512
#define F_OUT 256
#define NB_SCAN 157  // ceil(40000/256)

typedef unsigned short ushort_t;
typedef __attribute__((ext_vector_type(8))) short bf16x8;
typedef __attribute__((ext_vector_type(4))) float floatx4;

__device__ __forceinline__ ushort_t f2bf(float f) {
  union { float f; unsigned int u; } x; x.f = f;
  unsigned int r = (x.u + 0x7FFFu + ((x.u >> 16) & 1u)) >> 16;  // RNE
  return (ushort_t)r;
}
__device__ __forceinline__ float bf2f(ushort_t u) {
  union { unsigned int u; float f; } x; x.u = ((unsigned int)u) << 16;
  return x.f;
}

// ---------------- CSR build (scans + fill) ----------------
__global__ void scanA_kernel(const int* __restrict__ deg, int* __restrict__ bsum) {
  __shared__ int sdata[256];
  int i = blockIdx.x * 256 + threadIdx.x;
  sdata[threadIdx.x] = (i < N_NODES) ? deg[i] : 0;
  __syncthreads();
  #pragma unroll
  for (int off = 128; off > 0; off >>= 1) {
    if (threadIdx.x < off) sdata[threadIdx.x] += sdata[threadIdx.x + off];
    __syncthreads();
  }
  if (threadIdx.x == 0) bsum[blockIdx.x] = sdata[0];
}

__global__ void scanB_kernel(const int* __restrict__ bsum, int* __restrict__ boff) {
  __shared__ int buf[2][256];
  int tid = threadIdx.x;
  int v = (tid < NB_SCAN) ? bsum[tid] : 0;
  buf[0][tid] = v;
  __syncthreads();
  int cur = 0;
  #pragma unroll
  for (int off = 1; off < 256; off <<= 1) {
    int val = buf[cur][tid];
    if (tid >= off) val += buf[cur][tid - off];
    buf[cur ^ 1][tid] = val;
    __syncthreads();
    cur ^= 1;
  }
  if (tid < NB_SCAN) boff[tid] = buf[cur][tid] - v;  // exclusive
}

__global__ void scanC_kernel(const int* __restrict__ deg, const int* __restrict__ boff,
                             int* __restrict__ rowptr, int* __restrict__ cursor) {
  __shared__ int buf[2][256];
  int tid = threadIdx.x;
  int i = blockIdx.x * 256 + tid;
  int v = (i < N_NODES) ? deg[i] : 0;
  buf[0][tid] = v;
  __syncthreads();
  int cur = 0;
  #pragma unroll
  for (int off = 1; off < 256; off <<= 1) {
    int val = buf[cur][tid];
    if (tid >= off) val += buf[cur][tid - off];
    buf[cur ^ 1][tid] = val;
    __syncthreads();
    cur ^= 1;
  }
  if (i < N_NODES) {
    int ex = boff[blockIdx.x] + buf[cur][tid] - v;
    rowptr[i] = ex;
    cursor[i] = ex;
    if (i == N_NODES - 1) rowptr[N_NODES] = ex + v;  // == E
  }
}

__global__ void fill_kernel(const int* __restrict__ ei, int* __restrict__ cursor,
                            int* __restrict__ col) {
  int e = blockIdx.x * blockDim.x + threadIdx.x;
  if (e < N_EDGES) {
    int d = ei[N_EDGES + e];
    int s = ei[e];
    int pos = atomicAdd(&cursor[d], 1);
    col[pos] = s;
  }
}

// ---------------- fused preprocessing ----------------
// Wp pack: element (n_global = rowoff+n, k_global = koff+k) at
//   Wp[((gg*(KT/32) + t)*4 + ni)*512 + (qk*16 + lm)*8 + j]
// gg=n>>6, ni=(n>>4)&3, lm=n&15, c=kg>>3, t=c>>2, qk=c&3, j=kg&7.
__device__ __forceinline__ void wp_body(const float* __restrict__ W,
                                        ushort_t* __restrict__ Wp,
                                        int i, int K, int N, int rowoff, int koff,
                                        int KT) {
  if (i < K * N) {
    int n = i / K, k = i - n * K;
    int ng = rowoff + n, kg = koff + k;
    int gg = ng >> 6, ni = (ng >> 4) & 3, lm = ng & 15;
    int c = kg >> 3, j = kg & 7, t = c >> 2, qk = c & 3;
    size_t dst = (((size_t)(gg * (KT / 32) + t) * 4 + ni) * 64 + qk * 16 + lm) * 8 + j;
    Wp[dst] = f2bf(W[(size_t)k * N + n]);
  }
}

// block ranges: [0,5000) cvt_x | [5000,5256) W1l | [5256,5512) W1r
// [5512,6024) W2l | [6024,6536) W2r | [6536,6538) biascat | [6538,9038) deg
#define PREP_BLOCKS 9038
__global__ void prep_kernel(const float* __restrict__ x, ushort_t* __restrict__ xb,
                            const float* __restrict__ W1l, const float* __restrict__ W1r,
                            const float* __restrict__ W2l, const float* __restrict__ W2r,
                            ushort_t* __restrict__ Wp1, ushort_t* __restrict__ Wp2,
                            const float* __restrict__ b2, float* __restrict__ bc,
                            const int* __restrict__ ei, int* __restrict__ deg) {
  int b = blockIdx.x, tid = threadIdx.x;
  if (b < 5000) {
    int i = b * 256 + tid;  // per float4
    const int n4 = (N_NODES * F_IN) / 4;
    if (i < n4) {
      float4 v = ((const float4*)x)[i];
      ushort4 o;
      o.x = f2bf(v.x); o.y = f2bf(v.y); o.z = f2bf(v.z); o.w = f2bf(v.w);
      ((ushort4*)xb)[i] = o;
    }
  } else if (b < 5256) {
    wp_body(W1l, Wp1, (b - 5000) * 256 + tid, 128, 512, 0, 0, 256);
  } else if (b < 5512) {
    wp_body(W1r, Wp1, (b - 5256) * 256 + tid, 128, 512, 0, 128, 256);
  } else if (b < 6024) {
    wp_body(W2l, Wp2, (b - 5512) * 256 + tid, 512, 256, 0, 0, 512);
  } else if (b < 6536) {
    wp_body(W2r, Wp2, (b - 6024) * 256 + tid, 512, 256, 256, 0, 512);
  } else if (b < 6538) {
    int i = (b - 6536) * 256 + tid;
    if (i < 512) bc[i] = (i < 256) ? 0.f : b2[i - 256];
  } else {
    int e = (b - 6538) * 256 + tid;
    if (e < N_EDGES) atomicAdd(&deg[ei[N_EDGES + e]], 1);
  }
}

// ---------------- aggregation ----------------
// Node per block, full-row coalesced gathers, 8 loads in flight per thread.
__global__ void agg1_kernel(const ushort_t* __restrict__ Xb, ushort_t* __restrict__ Yb,
                            const int* __restrict__ rowptr, const int* __restrict__ colidx) {
  __shared__ int cols[64];
  int n = blockIdx.x, f = threadIdx.x;
  int s = rowptr[n], e = rowptr[n + 1];
  float s0 = 0.f, s1 = 0.f;
  for (int base = s; base < e; base += 64) {
    int cnt = min(64, e - base);
    __syncthreads();
    if (f < cnt) cols[f] = colidx[base + f];
    __syncthreads();
    int j = 0;
    for (; j + 8 <= cnt; j += 8) {  // 8 gathers in flight
      unsigned int v[8];
      #pragma unroll
      for (int u = 0; u < 8; ++u)
        v[u] = *(const unsigned int*)(Xb + (size_t)cols[j + u] * F_IN + 2 * f);
      #pragma unroll
      for (int u = 0; u < 8; ++u) {
        s0 += bf2f((ushort_t)(v[u] & 0xffffu));
        s1 += bf2f((ushort_t)(v[u] >> 16));
      }
    }
    for (; j < cnt; ++j) {
      unsigned int v = *(const unsigned int*)(Xb + (size_t)cols[j] * F_IN + 2 * f);
      s0 += bf2f((ushort_t)(v & 0xffffu));
      s1 += bf2f((ushort_t)(v >> 16));
    }
  }
  float inv = 1.f / fmaxf((float)(e - s), 1.f);
  unsigned int o = (unsigned int)f2bf(s0 * inv) | ((unsigned int)f2bf(s1 * inv) << 16);
  *(unsigned int*)(Yb + (size_t)n * F_IN + 2 * f) = o;
}

__global__ void agg2_kernel(const ushort_t* __restrict__ hl, const float* __restrict__ hr,
                            float* __restrict__ out,
                            const int* __restrict__ rowptr, const int* __restrict__ colidx) {
  __shared__ int cols[128];
  int n = blockIdx.x, f = threadIdx.x;
  int s = rowptr[n], e = rowptr[n + 1];
  float2 hrv = *(const float2*)(hr + (size_t)n * F_OUT + 2 * f);  // hoisted stream
  float s0 = 0.f, s1 = 0.f;
  for (int base = s; base < e; base += 128) {
    int cnt = min(128, e - base);
    __syncthreads();
    if (f < cnt) cols[f] = colidx[base + f];
    __syncthreads();
    int j = 0;
    for (; j + 8 <= cnt; j += 8) {  // 8 gathers in flight
      unsigned int v[8];
      #pragma unroll
      for (int u = 0; u < 8; ++u)
        v[u] = *(const unsigned int*)(hl + (size_t)cols[j + u] * F_OUT + 2 * f);
      #pragma unroll
      for (int u = 0; u < 8; ++u) {
        s0 += bf2f((ushort_t)(v[u] & 0xffffu));
        s1 += bf2f((ushort_t)(v[u] >> 16));
      }
    }
    for (; j < cnt; ++j) {
      unsigned int v = *(const unsigned int*)(hl + (size_t)cols[j] * F_OUT + 2 * f);
      s0 += bf2f((ushort_t)(v & 0xffffu));
      s1 += bf2f((ushort_t)(v >> 16));
    }
  }
  float inv = 1.f / fmaxf((float)(e - s), 1.f);
  float2 o;
  o.x = s0 * inv + hrv.x;
  o.y = s1 * inv + hrv.y;
  *(float2*)(out + (size_t)n * F_OUT + 2 * f) = o;
}

// ---------------- bf16 MFMA GEMM ----------------
// C[M, 512] = Acat[M, KT] @ Wcat[KT, 512] (+bias)(relu). Acat = [A0 | A1]
// when TWOPAIR (K0 = KT/2 each). Wp pre-packed per-lane (see wp_body).
// 512 threads / 8 waves; wave w owns cols w*64..w*64+63 (single N-block:
// the 64-row A panel is fetched ONCE per M-tile). BM=64, grid 625.
// A-panel staged in K-halves of 256 (Apan 32 KB; 2 blocks/CU, 16 waves/CU);
// layer 2 (KT=512) re-stages once mid-loop. XOR swizzle on ds_write/ds_read.
// B: register double-buffer, coalesced 1 KB wave-loads, no barriers in K-loop.
// Swapped-operand MFMA: acc[mi][ni] = mfma(bv, av, acc) -> lane's 4 acc regs
// are 4 consecutive output cols of one row -> vector epilogue stores.
// SPLITOUT: cols<256 -> Cb bf16 [M][256], cols>=256 -> Cf fp32 [M][256].
template <bool TWOPAIR, bool RELU, bool BIAS, bool OUT_BF16, bool SPLITOUT, int KT>
__global__ __launch_bounds__(512) void gemm_mfma(
    const ushort_t* __restrict__ A0, const ushort_t* __restrict__ A1,
    const ushort_t* __restrict__ Wp, const float* __restrict__ bias,
    float* __restrict__ Cf, ushort_t* __restrict__ Cb, int M) {
  const int KH = (KT > 256) ? 256 : KT;  // staged K extent: 32 KB LDS
  const int NH = KT / KH;                // 1 (layer 1) or 2 (layer 2)
  const int NKH = KH / 8;                // 16B chunks per row per stage = 32
  __shared__ ushort_t Apan[64 * KH];
  const int tid = threadIdx.x;
  const int wave = tid >> 6, lane = tid & 63;
  const int lm = lane & 15, qk = lane >> 4;
  const int bm = blockIdx.x * 64;    // 625 * 64 = 40000 exactly, no tail
  const int K0 = TWOPAIR ? KT / 2 : KT;
  const int K0c = K0 / 8;

  // per-wave B base: wave w == 64-col group gg=w in the packed layout
  const ushort_t* wpg = Wp + (size_t)wave * (KT / 32) * 2048;

  auto stageA = [&](int h) {
    #pragma unroll
    for (int q = 0; q < (64 * NKH) / 512; ++q) {
      int c = tid + q * 512;
      int lc = c & (NKH - 1);
      int row = c / NKH;
      int kc = h * NKH + lc;
      const ushort_t* src = (TWOPAIR && kc >= K0c)
          ? A1 + (size_t)(bm + row) * K0 + (kc - K0c) * 8
          : A0 + (size_t)(bm + row) * K0 + kc * 8;
      bf16x8 v = *(const bf16x8*)src;
      size_t off = ((size_t)(lc * 64 + row) * 16) ^ (size_t)((lc & 7) << 4);
      *(bf16x8*)((char*)Apan + off) = v;
    }
  };

  stageA(0);
  bf16x8 bvA[4], bvB[4];
  #pragma unroll
  for (int ni = 0; ni < 4; ++ni)
    bvA[ni] = *(const bf16x8*)(wpg + (size_t)ni * 512 + lane * 8);  // t=0
  __syncthreads();  // A half 0 visible

  floatx4 acc[4][4] = {};
  #pragma unroll 1
  for (int h = 0; h < NH; ++h) {
    if (h) {
      __syncthreads();   // everyone done reading previous half
      stageA(h);
      __syncthreads();   // new half visible (B prefetch stays in flight)
    }
    #pragma unroll 1
    for (int kb = 0; kb < KH; kb += 64) {
      const int t0 = (h * KH + kb) / 32;
      // prefetch second half-tile of this iteration (t0+1)
      #pragma unroll
      for (int ni = 0; ni < 4; ++ni)
        bvB[ni] = *(const bf16x8*)(wpg + ((size_t)(t0 + 1) * 4 + ni) * 512 + lane * 8);

      bf16x8 av[4];
      const int kc0 = kb / 8 + qk;
      #pragma unroll
      for (int mi = 0; mi < 4; ++mi) {
        size_t off = ((size_t)(kc0 * 64 + mi * 16 + lm) * 16) ^ (size_t)((kc0 & 7) << 4);
        av[mi] = *(const bf16x8*)((char*)Apan + off);
      }
      #pragma unroll
      for (int mi = 0; mi < 4; ++mi)
        #pragma unroll
        for (int ni = 0; ni < 4; ++ni)
          acc[mi][ni] = __builtin_amdgcn_mfma_f32_16x16x32_bf16(
              bvA[ni], av[mi], acc[mi][ni], 0, 0, 0);  // swapped operands

      // prefetch first half-tile of NEXT iteration (t0+2), uniform branch
      if (h * KH + kb + 64 < KT) {
        #pragma unroll
        for (int ni = 0; ni < 4; ++ni)
          bvA[ni] = *(const bf16x8*)(wpg + ((size_t)(t0 + 2) * 4 + ni) * 512 + lane * 8);
      }

      const int kc1 = kb / 8 + 4 + qk;
      #pragma unroll
      for (int mi = 0; mi < 4; ++mi) {
        size_t off = ((size_t)(kc1 * 64 + mi * 16 + lm) * 16) ^ (size_t)((kc1 & 7) << 4);
        av[mi] = *(const bf16x8*)((char*)Apan + off);
      }
      #pragma unroll
      for (int mi = 0; mi < 4; ++mi)
        #pragma unroll
        for (int ni = 0; ni < 4; ++ni)
          acc[mi][ni] = __builtin_amdgcn_mfma_f32_16x16x32_bf16(
              bvB[ni], av[mi], acc[mi][ni], 0, 0, 0);
    }
  }

  // ---- epilogue: row = bm + mi*16 + lm, cols = wave*64 + ni*16 + qk*4 ----
  #pragma unroll
  for (int ni = 0; ni < 4; ++ni) {
    int colg = wave * 64 + ni * 16 + qk * 4;
    float4 b4 = {0.f, 0.f, 0.f, 0.f};
    if (BIAS) b4 = *(const float4*)&bias[colg];
    #pragma unroll
    for (int mi = 0; mi < 4; ++mi) {
      int rowg = bm + mi * 16 + lm;
      float v0 = acc[mi][ni][0] + b4.x;
      float v1 = acc[mi][ni][1] + b4.y;
      float v2 = acc[mi][ni][2] + b4.z;
      float v3 = acc[mi][ni][3] + b4.w;
      if (RELU) {
        v0 = fmaxf(v0, 0.f); v1 = fmaxf(v1, 0.f);
        v2 = fmaxf(v2, 0.f); v3 = fmaxf(v3, 0.f);
      }
      if (SPLITOUT) {
        if (colg < 256) {
          ushort4 o = {f2bf(v0), f2bf(v1), f2bf(v2), f2bf(v3)};
          *(ushort4*)&Cb[(size_t)rowg * 256 + colg] = o;
        } else {
          float4 o = {v0, v1, v2, v3};
          *(float4*)&Cf[(size_t)rowg * 256 + (colg - 256)] = o;
        }
      } else if (OUT_BF16) {
        ushort4 o = {f2bf(v0), f2bf(v1), f2bf(v2), f2bf(v3)};
        *(ushort4*)&Cb[(size_t)rowg * 512 + colg] = o;
      } else {
        float4 o = {v0, v1, v2, v3};
        *(float4*)&Cf[(size_t)rowg * 512 + colg] = o;
      }
    }
  }
}

extern "C" void kernel_launch(void* const* d_in, const int* in_sizes, int n_in,
                              void* d_out, int out_size, void* d_ws, size_t ws_size,
                              hipStream_t stream) {
  const float* x = (const float*)d_in[0];
  const int* ei = (const int*)d_in[1];  // int32 per harness, [2][E]
  const float* W1l = (const float*)d_in[2];
  const float* b1 = (const float*)d_in[3];
  const float* W1r = (const float*)d_in[4];
  const float* W2l = (const float*)d_in[5];
  const float* b2 = (const float*)d_in[6];
  const float* W2r = (const float*)d_in[7];
  float* out = (float*)d_out;

  char* ws = (char*)d_ws;
  size_t off = 0;
  auto alloc = [&](size_t bytes) {
    void* p = ws + off;
    off = (off + bytes + 255) & ~(size_t)255;
    return p;
  };
  int* deg = (int*)alloc((size_t)N_NODES * 4);
  int* rowptr = (int*)alloc((size_t)(N_NODES + 1) * 4);
  int* cursor = (int*)alloc((size_t)N_NODES * 4);
  int* col = (int*)alloc((size_t)N_EDGES * 4);
  int* bsum = (int*)alloc((size_t)NB_SCAN * 4);
  int* boff = (int*)alloc((size_t)NB_SCAN * 4);
  ushort_t* x_bf = (ushort_t*)alloc((size_t)N_NODES * F_IN * 2);
  ushort_t* aggx_bf = (ushort_t*)alloc((size_t)N_NODES * F_IN * 2);
  ushort_t* h_bf = (ushort_t*)alloc((size_t)N_NODES * F_HID * 2);
  ushort_t* hl_bf = (ushort_t*)alloc((size_t)N_NODES * F_OUT * 2);  // h@W2l, bf16
  float* hr = (float*)alloc((size_t)N_NODES * F_OUT * 4);           // h@W2r + b2
  ushort_t* Wp1 = (ushort_t*)alloc((size_t)512 * 256 * 2);   // packed [W1l^T|W1r^T]
  ushort_t* Wp2 = (ushort_t*)alloc((size_t)512 * 512 * 2);   // packed [W2l|W2r]
  float* biascat = (float*)alloc(512 * 4);

  // Fused preprocessing: cvt_x + 4x wp + biascat + deg (independent work)
  hipMemsetAsync(deg, 0, (size_t)N_NODES * 4, stream);
  prep_kernel<<<PREP_BLOCKS, 256, 0, stream>>>(
      x, x_bf, W1l, W1r, W2l, W2r, Wp1, Wp2, b2, biascat, ei, deg);

  // CSR build
  scanA_kernel<<<NB_SCAN, 256, 0, stream>>>(deg, bsum);
  scanB_kernel<<<1, 256, 0, stream>>>(bsum, boff);
  scanC_kernel<<<NB_SCAN, 256, 0, stream>>>(deg, boff, rowptr, cursor);
  fill_kernel<<<(N_EDGES + 255) / 256, 256, 0, stream>>>(ei, cursor, col);

  // Layer 1: aggx_bf = mean-agg(x_bf); h_bf = relu([aggx|x] @ [W1l;W1r] + b1)
  agg1_kernel<<<N_NODES, 64, 0, stream>>>(x_bf, aggx_bf, rowptr, col);
  gemm_mfma<true, true, true, true, false, 256>
      <<<625, 512, 0, stream>>>(
          aggx_bf, x_bf, Wp1, b1, nullptr, h_bf, N_NODES);

  // Layer 2 fused: [hl_bf | hr] = h_bf @ [W2l|W2r] + [0|b2], split outputs
  gemm_mfma<false, false, true, false, true, 512>
      <<<625, 512, 0, stream>>>(
          h_bf, nullptr, Wp2, biascat, hr, hl_bf, N_NODES);
  // out = mean-agg(hl_bf) + hr
  agg2_kernel<<<N_NODES, 128, 0, stream>>>(hl_bf, hr, out, rowptr, col);
}

// Round 6
// 296.352 us; speedup vs baseline: 1.5127x; 1.0043x over previous
//
#include <hip/hip_runtime.h>

// GraphSAGE 2-layer. N=40000, E=640000, 128 -> 512 (relu) -> 256.
// Round 13: GEMM occupancy via grid supply. Round-12 counters: gemm2
// MfmaUtil 14%, Occupancy 16%, HBM 25% -- latency-bound because grid 625
// gives only 2.4 blocks/CU (resources would allow 4-5). Fix: BM=32,
// grid 1250 (4.9 blocks/CU -> ~32 waves/CU resident), still single
// N-block (A fetched once). Bonus: A panel = 32 x KT = 32 KB max -> the
// FULL K extent is staged for both layers; the layer-2 mid-loop re-stage
// and its 2 barriers are gone (exactly one __syncthreads per block).
// acc[2][4] (-32 VGPR). Accepted trade: B L2 traffic doubles (~640 MB
// total, L2-resident weights) -- hidden under the restored occupancy.
// prep/CSR/agg unchanged from round-12 (297.6 us).

#define N_NODES 40000
#define N_EDGES 640000
#define F_IN 128
#define F_HID 512
#define F_OUT 256
#define NB_SCAN 157  // ceil(40000/256)

typedef unsigned short ushort_t;
typedef __attribute__((ext_vector_type(8))) short bf16x8;
typedef __attribute__((ext_vector_type(4))) float floatx4;

__device__ __forceinline__ ushort_t f2bf(float f) {
  union { float f; unsigned int u; } x; x.f = f;
  unsigned int r = (x.u + 0x7FFFu + ((x.u >> 16) & 1u)) >> 16;  // RNE
  return (ushort_t)r;
}
__device__ __forceinline__ float bf2f(ushort_t u) {
  union { unsigned int u; float f; } x; x.u = ((unsigned int)u) << 16;
  return x.f;
}

// ---------------- CSR build (scans + fill) ----------------
__global__ void scanA_kernel(const int* __restrict__ deg, int* __restrict__ bsum) {
  __shared__ int sdata[256];
  int i = blockIdx.x * 256 + threadIdx.x;
  sdata[threadIdx.x] = (i < N_NODES) ? deg[i] : 0;
  __syncthreads();
  #pragma unroll
  for (int off = 128; off > 0; off >>= 1) {
    if (threadIdx.x < off) sdata[threadIdx.x] += sdata[threadIdx.x + off];
    __syncthreads();
  }
  if (threadIdx.x == 0) bsum[blockIdx.x] = sdata[0];
}

__global__ void scanB_kernel(const int* __restrict__ bsum, int* __restrict__ boff) {
  __shared__ int buf[2][256];
  int tid = threadIdx.x;
  int v = (tid < NB_SCAN) ? bsum[tid] : 0;
  buf[0][tid] = v;
  __syncthreads();
  int cur = 0;
  #pragma unroll
  for (int off = 1; off < 256; off <<= 1) {
    int val = buf[cur][tid];
    if (tid >= off) val += buf[cur][tid - off];
    buf[cur ^ 1][tid] = val;
    __syncthreads();
    cur ^= 1;
  }
  if (tid < NB_SCAN) boff[tid] = buf[cur][tid] - v;  // exclusive
}

__global__ void scanC_kernel(const int* __restrict__ deg, const int* __restrict__ boff,
                             int* __restrict__ rowptr, int* __restrict__ cursor) {
  __shared__ int buf[2][256];
  int tid = threadIdx.x;
  int i = blockIdx.x * 256 + tid;
  int v = (i < N_NODES) ? deg[i] : 0;
  buf[0][tid] = v;
  __syncthreads();
  int cur = 0;
  #pragma unroll
  for (int off = 1; off < 256; off <<= 1) {
    int val = buf[cur][tid];
    if (tid >= off) val += buf[cur][tid - off];
    buf[cur ^ 1][tid] = val;
    __syncthreads();
    cur ^= 1;
  }
  if (i < N_NODES) {
    int ex = boff[blockIdx.x] + buf[cur][tid] - v;
    rowptr[i] = ex;
    cursor[i] = ex;
    if (i == N_NODES - 1) rowptr[N_NODES] = ex + v;  // == E
  }
}

__global__ void fill_kernel(const int* __restrict__ ei, int* __restrict__ cursor,
                            int* __restrict__ col) {
  int e = blockIdx.x * blockDim.x + threadIdx.x;
  if (e < N_EDGES) {
    int d = ei[N_EDGES + e];
    int s = ei[e];
    int pos = atomicAdd(&cursor[d], 1);
    col[pos] = s;
  }
}

// ---------------- fused preprocessing ----------------
// Wp pack: element (n_global = rowoff+n, k_global = koff+k) at
//   Wp[((gg*(KT/32) + t)*4 + ni)*512 + (qk*16 + lm)*8 + j]
// gg=n>>6, ni=(n>>4)&3, lm=n&15, c=kg>>3, t=c>>2, qk=c&3, j=kg&7.
__device__ __forceinline__ void wp_body(const float* __restrict__ W,
                                        ushort_t* __restrict__ Wp,
                                        int i, int K, int N, int rowoff, int koff,
                                        int KT) {
  if (i < K * N) {
    int n = i / K, k = i - n * K;
    int ng = rowoff + n, kg = koff + k;
    int gg = ng >> 6, ni = (ng >> 4) & 3, lm = ng & 15;
    int c = kg >> 3, j = kg & 7, t = c >> 2, qk = c & 3;
    size_t dst = (((size_t)(gg * (KT / 32) + t) * 4 + ni) * 64 + qk * 16 + lm) * 8 + j;
    Wp[dst] = f2bf(W[(size_t)k * N + n]);
  }
}

// block ranges: [0,5000) cvt_x | [5000,5256) W1l | [5256,5512) W1r
// [5512,6024) W2l | [6024,6536) W2r | [6536,6538) biascat | [6538,9038) deg
#define PREP_BLOCKS 9038
__global__ void prep_kernel(const float* __restrict__ x, ushort_t* __restrict__ xb,
                            const float* __restrict__ W1l, const float* __restrict__ W1r,
                            const float* __restrict__ W2l, const float* __restrict__ W2r,
                            ushort_t* __restrict__ Wp1, ushort_t* __restrict__ Wp2,
                            const float* __restrict__ b2, float* __restrict__ bc,
                            const int* __restrict__ ei, int* __restrict__ deg) {
  int b = blockIdx.x, tid = threadIdx.x;
  if (b < 5000) {
    int i = b * 256 + tid;  // per float4
    const int n4 = (N_NODES * F_IN) / 4;
    if (i < n4) {
      float4 v = ((const float4*)x)[i];
      ushort4 o;
      o.x = f2bf(v.x); o.y = f2bf(v.y); o.z = f2bf(v.z); o.w = f2bf(v.w);
      ((ushort4*)xb)[i] = o;
    }
  } else if (b < 5256) {
    wp_body(W1l, Wp1, (b - 5000) * 256 + tid, 128, 512, 0, 0, 256);
  } else if (b < 5512) {
    wp_body(W1r, Wp1, (b - 5256) * 256 + tid, 128, 512, 0, 128, 256);
  } else if (b < 6024) {
    wp_body(W2l, Wp2, (b - 5512) * 256 + tid, 512, 256, 0, 0, 512);
  } else if (b < 6536) {
    wp_body(W2r, Wp2, (b - 6024) * 256 + tid, 512, 256, 256, 0, 512);
  } else if (b < 6538) {
    int i = (b - 6536) * 256 + tid;
    if (i < 512) bc[i] = (i < 256) ? 0.f : b2[i - 256];
  } else {
    int e = (b - 6538) * 256 + tid;
    if (e < N_EDGES) atomicAdd(&deg[ei[N_EDGES + e]], 1);
  }
}

// ---------------- aggregation ----------------
// Node per block, full-row coalesced gathers, 8 loads in flight per thread.
__global__ void agg1_kernel(const ushort_t* __restrict__ Xb, ushort_t* __restrict__ Yb,
                            const int* __restrict__ rowptr, const int* __restrict__ colidx) {
  __shared__ int cols[64];
  int n = blockIdx.x, f = threadIdx.x;
  int s = rowptr[n], e = rowptr[n + 1];
  float s0 = 0.f, s1 = 0.f;
  for (int base = s; base < e; base += 64) {
    int cnt = min(64, e - base);
    __syncthreads();
    if (f < cnt) cols[f] = colidx[base + f];
    __syncthreads();
    int j = 0;
    for (; j + 8 <= cnt; j += 8) {  // 8 gathers in flight
      unsigned int v[8];
      #pragma unroll
      for (int u = 0; u < 8; ++u)
        v[u] = *(const unsigned int*)(Xb + (size_t)cols[j + u] * F_IN + 2 * f);
      #pragma unroll
      for (int u = 0; u < 8; ++u) {
        s0 += bf2f((ushort_t)(v[u] & 0xffffu));
        s1 += bf2f((ushort_t)(v[u] >> 16));
      }
    }
    for (; j < cnt; ++j) {
      unsigned int v = *(const unsigned int*)(Xb + (size_t)cols[j] * F_IN + 2 * f);
      s0 += bf2f((ushort_t)(v & 0xffffu));
      s1 += bf2f((ushort_t)(v >> 16));
    }
  }
  float inv = 1.f / fmaxf((float)(e - s), 1.f);
  unsigned int o = (unsigned int)f2bf(s0 * inv) | ((unsigned int)f2bf(s1 * inv) << 16);
  *(unsigned int*)(Yb + (size_t)n * F_IN + 2 * f) = o;
}

__global__ void agg2_kernel(const ushort_t* __restrict__ hl, const float* __restrict__ hr,
                            float* __restrict__ out,
                            const int* __restrict__ rowptr, const int* __restrict__ colidx) {
  __shared__ int cols[128];
  int n = blockIdx.x, f = threadIdx.x;
  int s = rowptr[n], e = rowptr[n + 1];
  float2 hrv = *(const float2*)(hr + (size_t)n * F_OUT + 2 * f);  // hoisted stream
  float s0 = 0.f, s1 = 0.f;
  for (int base = s; base < e; base += 128) {
    int cnt = min(128, e - base);
    __syncthreads();
    if (f < cnt) cols[f] = colidx[base + f];
    __syncthreads();
    int j = 0;
    for (; j + 8 <= cnt; j += 8) {  // 8 gathers in flight
      unsigned int v[8];
      #pragma unroll
      for (int u = 0; u < 8; ++u)
        v[u] = *(const unsigned int*)(hl + (size_t)cols[j + u] * F_OUT + 2 * f);
      #pragma unroll
      for (int u = 0; u < 8; ++u) {
        s0 += bf2f((ushort_t)(v[u] & 0xffffu));
        s1 += bf2f((ushort_t)(v[u] >> 16));
      }
    }
    for (; j < cnt; ++j) {
      unsigned int v = *(const unsigned int*)(hl + (size_t)cols[j] * F_OUT + 2 * f);
      s0 += bf2f((ushort_t)(v & 0xffffu));
      s1 += bf2f((ushort_t)(v >> 16));
    }
  }
  float inv = 1.f / fmaxf((float)(e - s), 1.f);
  float2 o;
  o.x = s0 * inv + hrv.x;
  o.y = s1 * inv + hrv.y;
  *(float2*)(out + (size_t)n * F_OUT + 2 * f) = o;
}

// ---------------- bf16 MFMA GEMM ----------------
// C[M, 512] = Acat[M, KT] @ Wcat[KT, 512] (+bias)(relu). Acat = [A0 | A1]
// when TWOPAIR (K0 = KT/2 each). Wp pre-packed per-lane (see wp_body).
// BM=32, grid 1250, 512 threads / 8 waves; wave w owns cols w*64..w*64+63.
// Full-K A panel staged once (32 x KT = 16/32 KB LDS); ONE barrier per
// block; barrier-free K-loop with register double-buffered B (coalesced
// 1 KB wave-loads from the packed layout). XOR swizzle on ds_write/read.
// Swapped-operand MFMA: acc[mi][ni] = mfma(bv, av, acc) -> lane's 4 acc
// regs are 4 consecutive output cols of one row -> vector epilogue stores.
// SPLITOUT: cols<256 -> Cb bf16 [M][256], cols>=256 -> Cf fp32 [M][256].
template <bool TWOPAIR, bool RELU, bool BIAS, bool OUT_BF16, bool SPLITOUT, int KT>
__global__ __launch_bounds__(512) void gemm_mfma(
    const ushort_t* __restrict__ A0, const ushort_t* __restrict__ A1,
    const ushort_t* __restrict__ Wp, const float* __restrict__ bias,
    float* __restrict__ Cf, ushort_t* __restrict__ Cb, int M) {
  const int NKC = KT / 8;            // 16B chunks per row (32 or 64)
  __shared__ ushort_t Apan[32 * KT]; // kc-major + XOR swizzle
  const int tid = threadIdx.x;
  const int wave = tid >> 6, lane = tid & 63;
  const int lm = lane & 15, qk = lane >> 4;
  const int bm = blockIdx.x * 32;    // 1250 * 32 = 40000 exactly, no tail
  const int K0 = TWOPAIR ? KT / 2 : KT;
  const int K0c = K0 / 8;

  // per-wave B base: wave w == 64-col group gg=w in the packed layout
  const ushort_t* wpg = Wp + (size_t)wave * (KT / 32) * 2048;

  // ---- stage full A panel: coalesced global read -> swizzled ds_write ----
  #pragma unroll
  for (int q = 0; q < (32 * NKC) / 512; ++q) {
    int c = tid + q * 512;
    int lc = c & (NKC - 1);
    int row = c / NKC;
    const ushort_t* src = (TWOPAIR && lc >= K0c)
        ? A1 + (size_t)(bm + row) * K0 + (lc - K0c) * 8
        : A0 + (size_t)(bm + row) * K0 + lc * 8;
    bf16x8 v = *(const bf16x8*)src;
    size_t off = ((size_t)(lc * 32 + row) * 16) ^ (size_t)((lc & 7) << 4);
    *(bf16x8*)((char*)Apan + off) = v;
  }

  bf16x8 bvA[4], bvB[4];
  #pragma unroll
  for (int ni = 0; ni < 4; ++ni)
    bvA[ni] = *(const bf16x8*)(wpg + (size_t)ni * 512 + lane * 8);  // t=0
  __syncthreads();  // the ONLY barrier: A panel visible

  floatx4 acc[2][4] = {};
  #pragma unroll 1
  for (int kb = 0; kb < KT; kb += 64) {
    const int t0 = kb / 32;
    // prefetch second half-tile of this iteration (t0+1)
    #pragma unroll
    for (int ni = 0; ni < 4; ++ni)
      bvB[ni] = *(const bf16x8*)(wpg + ((size_t)(t0 + 1) * 4 + ni) * 512 + lane * 8);

    bf16x8 av[2];
    const int kc0 = kb / 8 + qk;
    #pragma unroll
    for (int mi = 0; mi < 2; ++mi) {
      size_t off = ((size_t)(kc0 * 32 + mi * 16 + lm) * 16) ^ (size_t)((kc0 & 7) << 4);
      av[mi] = *(const bf16x8*)((char*)Apan + off);
    }
    #pragma unroll
    for (int mi = 0; mi < 2; ++mi)
      #pragma unroll
      for (int ni = 0; ni < 4; ++ni)
        acc[mi][ni] = __builtin_amdgcn_mfma_f32_16x16x32_bf16(
            bvA[ni], av[mi], acc[mi][ni], 0, 0, 0);  // swapped operands

    // prefetch first half-tile of NEXT iteration (t0+2), uniform branch
    if (kb + 64 < KT) {
      #pragma unroll
      for (int ni = 0; ni < 4; ++ni)
        bvA[ni] = *(const bf16x8*)(wpg + ((size_t)(t0 + 2) * 4 + ni) * 512 + lane * 8);
    }

    const int kc1 = kb / 8 + 4 + qk;
    #pragma unroll
    for (int mi = 0; mi < 2; ++mi) {
      size_t off = ((size_t)(kc1 * 32 + mi * 16 + lm) * 16) ^ (size_t)((kc1 & 7) << 4);
      av[mi] = *(const bf16x8*)((char*)Apan + off);
    }
    #pragma unroll
    for (int mi = 0; mi < 2; ++mi)
      #pragma unroll
      for (int ni = 0; ni < 4; ++ni)
        acc[mi][ni] = __builtin_amdgcn_mfma_f32_16x16x32_bf16(
            bvB[ni], av[mi], acc[mi][ni], 0, 0, 0);
  }

  // ---- epilogue: row = bm + mi*16 + lm, cols = wave*64 + ni*16 + qk*4 ----
  #pragma unroll
  for (int ni = 0; ni < 4; ++ni) {
    int colg = wave * 64 + ni * 16 + qk * 4;
    float4 b4 = {0.f, 0.f, 0.f, 0.f};
    if (BIAS) b4 = *(const float4*)&bias[colg];
    #pragma unroll
    for (int mi = 0; mi < 2; ++mi) {
      int rowg = bm + mi * 16 + lm;
      float v0 = acc[mi][ni][0] + b4.x;
      float v1 = acc[mi][ni][1] + b4.y;
      float v2 = acc[mi][ni][2] + b4.z;
      float v3 = acc[mi][ni][3] + b4.w;
      if (RELU) {
        v0 = fmaxf(v0, 0.f); v1 = fmaxf(v1, 0.f);
        v2 = fmaxf(v2, 0.f); v3 = fmaxf(v3, 0.f);
      }
      if (SPLITOUT) {
        if (colg < 256) {
          ushort4 o = {f2bf(v0), f2bf(v1), f2bf(v2), f2bf(v3)};
          *(ushort4*)&Cb[(size_t)rowg * 256 + colg] = o;
        } else {
          float4 o = {v0, v1, v2, v3};
          *(float4*)&Cf[(size_t)rowg * 256 + (colg - 256)] = o;
        }
      } else if (OUT_BF16) {
        ushort4 o = {f2bf(v0), f2bf(v1), f2bf(v2), f2bf(v3)};
        *(ushort4*)&Cb[(size_t)rowg * 512 + colg] = o;
      } else {
        float4 o = {v0, v1, v2, v3};
        *(float4*)&Cf[(size_t)rowg * 512 + colg] = o;
      }
    }
  }
}

extern "C" void kernel_launch(void* const* d_in, const int* in_sizes, int n_in,
                              void* d_out, int out_size, void* d_ws, size_t ws_size,
                              hipStream_t stream) {
  const float* x = (const float*)d_in[0];
  const int* ei = (const int*)d_in[1];  // int32 per harness, [2][E]
  const float* W1l = (const float*)d_in[2];
  const float* b1 = (const float*)d_in[3];
  const float* W1r = (const float*)d_in[4];
  const float* W2l = (const float*)d_in[5];
  const float* b2 = (const float*)d_in[6];
  const float* W2r = (const float*)d_in[7];
  float* out = (float*)d_out;

  char* ws = (char*)d_ws;
  size_t off = 0;
  auto alloc = [&](size_t bytes) {
    void* p = ws + off;
    off = (off + bytes + 255) & ~(size_t)255;
    return p;
  };
  int* deg = (int*)alloc((size_t)N_NODES * 4);
  int* rowptr = (int*)alloc((size_t)(N_NODES + 1) * 4);
  int* cursor = (int*)alloc((size_t)N_NODES * 4);
  int* col = (int*)alloc((size_t)N_EDGES * 4);
  int* bsum = (int*)alloc((size_t)NB_SCAN * 4);
  int* boff = (int*)alloc((size_t)NB_SCAN * 4);
  ushort_t* x_bf = (ushort_t*)alloc((size_t)N_NODES * F_IN * 2);
  ushort_t* aggx_bf = (ushort_t*)alloc((size_t)N_NODES * F_IN * 2);
  ushort_t* h_bf = (ushort_t*)alloc((size_t)N_NODES * F_HID * 2);
  ushort_t* hl_bf = (ushort_t*)alloc((size_t)N_NODES * F_OUT * 2);  // h@W2l, bf16
  float* hr = (float*)alloc((size_t)N_NODES * F_OUT * 4);           // h@W2r + b2
  ushort_t* Wp1 = (ushort_t*)alloc((size_t)512 * 256 * 2);   // packed [W1l^T|W1r^T]
  ushort_t* Wp2 = (ushort_t*)alloc((size_t)512 * 512 * 2);   // packed [W2l|W2r]
  float* biascat = (float*)alloc(512 * 4);

  // Fused preprocessing: cvt_x + 4x wp + biascat + deg (independent work)
  hipMemsetAsync(deg, 0, (size_t)N_NODES * 4, stream);
  prep_kernel<<<PREP_BLOCKS, 256, 0, stream>>>(
      x, x_bf, W1l, W1r, W2l, W2r, Wp1, Wp2, b2, biascat, ei, deg);

  // CSR build
  scanA_kernel<<<NB_SCAN, 256, 0, stream>>>(deg, bsum);
  scanB_kernel<<<1, 256, 0, stream>>>(bsum, boff);
  scanC_kernel<<<NB_SCAN, 256, 0, stream>>>(deg, boff, rowptr, cursor);
  fill_kernel<<<(N_EDGES + 255) / 256, 256, 0, stream>>>(ei, cursor, col);

  // Layer 1: aggx_bf = mean-agg(x_bf); h_bf = relu([aggx|x] @ [W1l;W1r] + b1)
  agg1_kernel<<<N_NODES, 64, 0, stream>>>(x_bf, aggx_bf, rowptr, col);
  gemm_mfma<true, true, true, true, false, 256>
      <<<1250, 512, 0, stream>>>(
          aggx_bf, x_bf, Wp1, b1, nullptr, h_bf, N_NODES);

  // Layer 2 fused: [hl_bf | hr] = h_bf @ [W2l|W2r] + [0|b2], split outputs
  gemm_mfma<false, false, true, false, true, 512>
      <<<1250, 512, 0, stream>>>(
          h_bf, nullptr, Wp2, biascat, hr, hl_bf, N_NODES);
  // out = mean-agg(hl_bf) + hr
  agg2_kernel<<<N_NODES, 128, 0, stream>>>(hl_bf, hr, out, rowptr, col);
}